// Round 13
// baseline (184.484 us; speedup 1.0000x reference)
//
#include <hip/hip_runtime.h>

// Problem dims
constexpr int Bb = 64;     // batch
constexpr int Tt = 256;    // timesteps
constexpr int Dd = 512;    // input dim (K)
constexpr int Hh = 1024;   // hidden (N)
constexpr int Mm = Bb * Tt;  // 16384 GEMM rows

typedef _Float16 half8 __attribute__((ext_vector_type(8)));
typedef float floatx16 __attribute__((ext_vector_type(16)));

#define GPTR(x) ((const __attribute__((address_space(1))) void*)(x))
#define LPTR(x) ((__attribute__((address_space(3))) void*)(x))

// ---------------------------------------------------------------------------
// Kernel 1 (tiny): W_in fp32 -> f16 hi/lo, chunk-transposed (chunk g =
// kc*1024 + row holds W[row][kc*8..+8) as 8 halves). One wave-unit = 64 rows
// x one kc-pair; 16 rowgroups x 32 kcpairs = 512 units = 128 blocks.
// Also initializes out[b] = b_out (out re-poisoned before every launch).
// x is NOT converted: the GEMM stages fp32 x directly and splits in-register.
// ---------------------------------------------------------------------------
__global__ __launch_bounds__(256) void convert_w(const float* __restrict__ Win,
                                                 _Float16* __restrict__ wh,
                                                 _Float16* __restrict__ wl,
                                                 const float* __restrict__ bout,
                                                 float* __restrict__ out) {
    const int tid = threadIdx.x;
    if (blockIdx.x == 0 && tid < Bb) out[tid] = bout[0];

    const int gw = (blockIdx.x * 256 + tid) >> 6;   // 0..511
    const int lane = tid & 63;
    const int kcp = gw >> 4;    // 0..31
    const int rg  = gw & 15;    // 0..15
    const int row = rg * 64 + lane;
    const float* p = Win + (size_t)row * Dd + kcp * 16;

    const float4 v0 = ((const float4*)p)[0];
    const float4 v1 = ((const float4*)p)[1];
    const float4 v2 = ((const float4*)p)[2];
    const float4 v3 = ((const float4*)p)[3];
    const float va[16] = {v0.x, v0.y, v0.z, v0.w, v1.x, v1.y, v1.z, v1.w,
                          v2.x, v2.y, v2.z, v2.w, v3.x, v3.y, v3.z, v3.w};
    half8 h[2], l[2];
#pragma unroll
    for (int c = 0; c < 2; ++c)
#pragma unroll
        for (int q = 0; q < 8; ++q) {
            const float v = va[c * 8 + q];
            const _Float16 hi = (_Float16)v;
            h[c][q] = hi;
            l[c][q] = (_Float16)((v - (float)hi) * 4096.0f);
        }
#pragma unroll
    for (int c = 0; c < 2; ++c) {
        const size_t g = (size_t)(kcp * 2 + c) * Hh + row;
        *(half8*)(wh + g * 8) = h[c];
        *(half8*)(wl + g * 8) = l[c];
    }
}

// ---------------------------------------------------------------------------
// Kernel 2: FUSED MFMA GEMM + ALIF scan (R9 structure, best measured) with
// IN-REGISTER A hi/lo split: A staged as RAW FP32 x (same bytes as hi+lo)
// via global_load_lds, chunk-major [kq 0..7][row 0..255] of 16B float4
// chunks (ds_read 16B-stride pattern = R9-proven conflict-free); the hi/lo
// split happens at fragment-read time (~4 VALU ops/elem, ~3.4us device-wide,
// hidden under MFMA). Eliminates the 33MB+33MB x-convert kernel entirely.
// Tile M=256 (one batch b) x N=64, 4 waves; B (wh/wl) direct global->reg
// 1-ahead; epilogue: dump C into two stride-32 LDS scan buffers, wave 0
// scans 64 h, one atomicAdd into out[b]. XCD swizzle: 16 n-blocks of one
// batch share one XCD (A fetched once device-wide).
// ---------------------------------------------------------------------------
__global__ __launch_bounds__(256, 2) void gemm_fused(const float* __restrict__ x,
                                                     const _Float16* __restrict__ wh,
                                                     const _Float16* __restrict__ wl,
                                                     const float* __restrict__ bin,
                                                     const float* __restrict__ Wout,
                                                     float* __restrict__ out) {
    __shared__ float ldsA[2][8192];  // [buf][8 kq x 256 rows x 4 floats] = 64KB

    const int tid = threadIdx.x;
    // XCD swizzle: j = id%8 = XCD slot; batch b ≡ j (mod 8); n-tile fast.
    const int id = blockIdx.x;          // 0..1023
    const int j  = id & 7;
    const int q  = id >> 3;             // 0..127
    const int nt = q & 15;              // n-tile 0..15 (64 cols each)
    const int b  = (q >> 4) * 8 + j;    // batch 0..63
    const int m0 = b * Tt;              // = b*256
    const int n0 = nt * 64;

    const int lane = tid & 63;
    const int wave = tid >> 6;          // 0..3, owns rows [64w, 64w+64)
    const int lr = lane & 31;
    const int lk = lane >> 5;

    floatx16 acc[2][2], accx[2][2];
#pragma unroll
    for (int mi = 0; mi < 2; ++mi)
#pragma unroll
        for (int ni = 0; ni < 2; ++ni)
#pragma unroll
            for (int r = 0; r < 16; ++r) { acc[mi][ni][r] = 0.0f; accx[mi][ni][r] = 0.0f; }

    // --- A staging: stage ss covers k [ss*32, ss*32+32) as fp32.
    // Thread tid stages row=tid, kq 0..7 (4 floats = 16B each), chunk-major.
#define STAGE_A(buf, k0)                                                             \
    do {                                                                             \
        _Pragma("unroll")                                                            \
        for (int kq_ = 0; kq_ < 8; ++kq_) {                                          \
            const float* ga_ = x + (size_t)(m0 + tid) * Dd + (k0) + kq_ * 4;         \
            __builtin_amdgcn_global_load_lds(GPTR(ga_),                              \
                LPTR(&ldsA[buf][(kq_ * 256 + tid) * 4]), 16, 0, 0);                  \
        }                                                                            \
    } while (0)

    // --- B direct loads: half-stage hs, k-chunk = hs*2 + lk ---
    const size_t bbase = (size_t)(n0 + lr) * 8;
    half8 bset[2][4];  // [rot][bh0, bh1, bl0, bl1]
#define LOAD_B(rot, hs)                                                              \
    do {                                                                             \
        const size_t off_ = (size_t)((hs) * 2 + lk) * (Hh * 8) + bbase;              \
        bset[rot][0] = *(const half8*)(wh + off_);                                   \
        bset[rot][1] = *(const half8*)(wh + off_ + 256);                             \
        bset[rot][2] = *(const half8*)(wl + off_);                                   \
        bset[rot][3] = *(const half8*)(wl + off_ + 256);                             \
    } while (0)

    STAGE_A(0, 0);
    LOAD_B(0, 0);

    for (int ss = 0; ss < 16; ++ss) {
        __syncthreads();  // A(ss) staged; buf safe to overwrite after this
        if (ss < 15) STAGE_A((ss + 1) & 1, (ss + 1) * 32);
        const int cur = ss & 1;
#pragma unroll
        for (int s2 = 0; s2 < 2; ++s2) {
            const int hs = ss * 2 + s2;
            const int rot = hs & 1;
            if (hs < 31) LOAD_B(rot ^ 1, hs + 1);

            half8 ah[2], al[2];
#pragma unroll
            for (int mi = 0; mi < 2; ++mi) {
                const int fr = wave * 64 + mi * 32 + lr;      // fragment row
                const int kqb = s2 * 4 + lk * 2;              // k offset: 8 floats
                const float4 f0 = *(const float4*)&ldsA[cur][(kqb * 256 + fr) * 4];
                const float4 f1 = *(const float4*)&ldsA[cur][((kqb + 1) * 256 + fr) * 4];
                const float fa[8] = {f0.x, f0.y, f0.z, f0.w, f1.x, f1.y, f1.z, f1.w};
#pragma unroll
                for (int e = 0; e < 8; ++e) {
                    const _Float16 hi = (_Float16)fa[e];
                    ah[mi][e] = hi;
                    al[mi][e] = (_Float16)((fa[e] - (float)hi) * 4096.0f);
                }
            }
#pragma unroll
            for (int mi = 0; mi < 2; ++mi)
#pragma unroll
                for (int ni = 0; ni < 2; ++ni) {
                    acc[mi][ni]  = __builtin_amdgcn_mfma_f32_32x32x16_f16(ah[mi], bset[rot][ni],     acc[mi][ni], 0, 0, 0);
                    accx[mi][ni] = __builtin_amdgcn_mfma_f32_32x32x16_f16(ah[mi], bset[rot][2 + ni], accx[mi][ni], 0, 0, 0);
                    accx[mi][ni] = __builtin_amdgcn_mfma_f32_32x32x16_f16(al[mi], bset[rot][ni],     accx[mi][ni], 0, 0, 0);
                }
        }
    }
#undef STAGE_A
#undef LOAD_B

    // ---------------- fused ALIF scan epilogue (R9-proven) ----------------
    __syncthreads();  // all K-loop LDS reads done; reuse ldsA as 2 scan buffers
    float* scanbuf = (float*)ldsA;  // buffer p at offset p*8192 floats (stride 32)

#pragma unroll
    for (int p = 0; p < 2; ++p) {
        const float bv = bin[n0 + p * 32 + lr];
        // C/D layout (32x32): col = lane&31, row = (r&3) + 8*(r>>2) + 4*lk
#pragma unroll
        for (int mi = 0; mi < 2; ++mi)
#pragma unroll
            for (int r = 0; r < 16; ++r) {
                const int row = (r & 3) + 8 * (r >> 2) + 4 * lk;
                const int t = wave * 64 + mi * 32 + row;   // m_local == timestep
                scanbuf[p * 8192 + t * 32 + lr] =
                    acc[mi][p][r] + accx[mi][p][r] * (1.0f / 4096.0f) + bv;
            }
    }
    __syncthreads();

    // Wave 0 scans all 64 h (lane = h - n0); waves 1-3 exit immediately.
    if (wave == 0) {
        const float* sb = scanbuf + (lane >> 5) * 8192 + (lane & 31);
        float mem = 0.0f, adapt = 0.0f, cnt = 0.0f;
#pragma unroll 8
        for (int t = 0; t < Tt; ++t) {
            const float v = sb[t * 32];
            mem = 0.9f * mem + v - adapt;
            const float spk = (mem > 0.0f) ? 1.0f : 0.0f;
            adapt += 0.1f * spk;
            mem -= spk;
            cnt += spk;
        }
        float val = cnt * Wout[n0 + lane] * (1.0f / (float)Tt);
#pragma unroll
        for (int off = 32; off > 0; off >>= 1) val += __shfl_down(val, off, 64);
        if (lane == 0) atomicAdd(&out[b], val);
    }
}

// ---------------------------------------------------------------------------
// Fallback fp32 SIMT GEMM + scan (proven) in case ws is too small.
// ---------------------------------------------------------------------------
#define BK 16
#define BMP 132
__global__ __launch_bounds__(256) void gemm_pre(const float* __restrict__ x,
                                                const float* __restrict__ Win,
                                                const float* __restrict__ bin,
                                                float* __restrict__ pre) {
    __shared__ float As[BK][BMP];
    __shared__ float Bs[BK][BMP];
    const int tid = threadIdx.x;
    const int m0 = blockIdx.y * 128;
    const int n0 = blockIdx.x * 128;
    const int tx = tid & 15;
    const int ty = tid >> 4;
    float acc[8][8];
#pragma unroll
    for (int i = 0; i < 8; ++i)
#pragma unroll
        for (int jj = 0; jj < 8; ++jj) acc[i][jj] = 0.0f;
    const float* Aptr = x + (size_t)m0 * Dd;
    const float* Bptr = Win + (size_t)n0 * Dd;
    for (int k0 = 0; k0 < Dd; k0 += BK) {
#pragma unroll
        for (int i = 0; i < 2; ++i) {
            const int lin = tid + i * 256;
            const int row = lin >> 2;
            const int kq = (lin & 3) << 2;
            const float4 av = *(const float4*)(Aptr + (size_t)row * Dd + k0 + kq);
            const float4 bv = *(const float4*)(Bptr + (size_t)row * Dd + k0 + kq);
            As[kq + 0][row] = av.x; As[kq + 1][row] = av.y;
            As[kq + 2][row] = av.z; As[kq + 3][row] = av.w;
            Bs[kq + 0][row] = bv.x; Bs[kq + 1][row] = bv.y;
            Bs[kq + 2][row] = bv.z; Bs[kq + 3][row] = bv.w;
        }
        __syncthreads();
#pragma unroll
        for (int kk = 0; kk < BK; ++kk) {
            const float4 a0 = *(const float4*)&As[kk][ty * 4];
            const float4 a1 = *(const float4*)&As[kk][ty * 4 + 64];
            const float4 b0 = *(const float4*)&Bs[kk][tx * 4];
            const float4 b1 = *(const float4*)&Bs[kk][tx * 4 + 64];
            const float a[8] = {a0.x, a0.y, a0.z, a0.w, a1.x, a1.y, a1.z, a1.w};
            const float b[8] = {b0.x, b0.y, b0.z, b0.w, b1.x, b1.y, b1.z, b1.w};
#pragma unroll
            for (int i = 0; i < 8; ++i)
#pragma unroll
                for (int jj = 0; jj < 8; ++jj) acc[i][jj] += a[i] * b[jj];
        }
        __syncthreads();
    }
#pragma unroll
    for (int i = 0; i < 8; ++i) {
        const int m = m0 + ((i < 4) ? (ty * 4 + i) : (64 + ty * 4 + i - 4));
#pragma unroll
        for (int half = 0; half < 2; ++half) {
            const int n = n0 + tx * 4 + half * 64;
            float4 v;
            v.x = acc[i][half * 4 + 0] + bin[n + 0];
            v.y = acc[i][half * 4 + 1] + bin[n + 1];
            v.z = acc[i][half * 4 + 2] + bin[n + 2];
            v.w = acc[i][half * 4 + 3] + bin[n + 3];
            *(float4*)(pre + (size_t)m * Hh + n) = v;
        }
    }
}

__global__ __launch_bounds__(64) void init_out(const float* __restrict__ bout,
                                               float* __restrict__ out) {
    out[threadIdx.x] = bout[0];
}

__global__ __launch_bounds__(64) void alif_scan(const float* __restrict__ pre,
                                                const float* __restrict__ Wout,
                                                float* __restrict__ out) {
    const int h = blockIdx.x * 64 + threadIdx.x;
    const int b = blockIdx.y;
    const float* p = pre + (size_t)b * Tt * Hh + h;

    float buf[32];
#pragma unroll
    for (int jj = 0; jj < 32; ++jj) buf[jj] = p[(size_t)jj * Hh];

    float mem = 0.0f, adapt = 0.0f, cnt = 0.0f;
    for (int t0 = 0; t0 < Tt; t0 += 32) {
        float cur[32];
#pragma unroll
        for (int jj = 0; jj < 32; ++jj) cur[jj] = buf[jj];
        if (t0 + 32 < Tt) {
#pragma unroll
            for (int jj = 0; jj < 32; ++jj) buf[jj] = p[(size_t)(t0 + 32 + jj) * Hh];
        }
#pragma unroll
        for (int jj = 0; jj < 32; ++jj) {
            mem = 0.9f * mem + cur[jj] - adapt;
            const float spk = (mem > 0.0f) ? 1.0f : 0.0f;
            adapt += 0.1f * spk;
            mem -= spk;
            cnt += spk;
        }
    }

    float val = cnt * Wout[h] * (1.0f / (float)Tt);
#pragma unroll
    for (int off = 32; off > 0; off >>= 1) val += __shfl_down(val, off, 64);
    if (threadIdx.x == 0) atomicAdd(&out[b], val);
}

extern "C" void kernel_launch(void* const* d_in, const int* in_sizes, int n_in,
                              void* d_out, int out_size, void* d_ws, size_t ws_size,
                              hipStream_t stream) {
    const float* x    = (const float*)d_in[0];
    const float* Win  = (const float*)d_in[1];
    const float* bin  = (const float*)d_in[2];
    const float* Wout = (const float*)d_in[3];
    const float* bout = (const float*)d_in[4];
    float* out = (float*)d_out;

    const size_t wh_bytes = (size_t)Hh * Dd * 2;   // 1 MiB
    const size_t need = 2 * wh_bytes + 4096;       // ~2 MiB only

    if (ws_size >= need) {
        _Float16* wh = (_Float16*)d_ws;
        _Float16* wl = (_Float16*)((char*)d_ws + wh_bytes);

        convert_w<<<128, 256, 0, stream>>>(Win, wh, wl, bout, out);
        gemm_fused<<<1024, 256, 0, stream>>>(x, wh, wl, bin, Wout, out);
    } else {
        float* pre = (float*)d_ws;  // needs 64 MiB
        init_out<<<1, 64, 0, stream>>>(bout, out);
        dim3 g1(Hh / 128, Mm / 128);
        gemm_pre<<<g1, 256, 0, stream>>>(x, Win, bin, pre);
        alif_scan<<<dim3(Hh / 64, Bb), 64, 0, stream>>>(pre, Wout, out);
    }
}

// Round 14
// 142.136 us; speedup vs baseline: 1.2979x; 1.2979x over previous
//
#include <hip/hip_runtime.h>

// Problem dims
constexpr int Bb = 64;     // batch
constexpr int Tt = 256;    // timesteps
constexpr int Dd = 512;    // input dim (K)
constexpr int Hh = 1024;   // hidden (N)
constexpr int Mm = Bb * Tt;  // 16384 GEMM rows

typedef _Float16 half8 __attribute__((ext_vector_type(8)));
typedef _Float16 half4v __attribute__((ext_vector_type(4)));
typedef float floatx16 __attribute__((ext_vector_type(16)));

#define GPTR(x) ((const __attribute__((address_space(1))) void*)(x))
#define LPTR(x) ((__attribute__((address_space(3))) void*)(x))

// ---------------------------------------------------------------------------
// Kernel 1: fp32 -> f16 hi/lo split, chunk-transposed (R9-proven).
// Output chunk g = kc*nrows + row holds src[row][kc*8..+8) as 8 halves, so
// GEMM A-fragment direct loads and B glds staging are coalesced.
// Also initializes out[b] = b_out (out is re-poisoned before every launch).
// ---------------------------------------------------------------------------
__global__ __launch_bounds__(256) void convert_t(const float* __restrict__ x,
                                                 const float* __restrict__ Win,
                                                 _Float16* __restrict__ xh,
                                                 _Float16* __restrict__ xl,
                                                 _Float16* __restrict__ wh,
                                                 _Float16* __restrict__ wl,
                                                 const float* __restrict__ bout,
                                                 float* __restrict__ out) {
    __shared__ _Float16 lh[64 * 72];
    __shared__ _Float16 ll[64 * 72];
    const int tid = threadIdx.x;
    const int k0 = blockIdx.x * 64;

    if (blockIdx.x == 0 && blockIdx.y == 0 && tid < Bb) out[tid] = bout[0];

    const float* src;
    _Float16 *dh, *dl;
    int nrows, m0;
    if (blockIdx.y < 256) {
        src = x; dh = xh; dl = xl; nrows = Mm; m0 = blockIdx.y * 64;
    } else {
        src = Win; dh = wh; dl = wl; nrows = Hh; m0 = (blockIdx.y - 256) * 64;
    }

#pragma unroll
    for (int i = 0; i < 4; ++i) {
        const int lin = tid + i * 256;
        const int row = lin >> 4;
        const int c4 = (lin & 15) * 4;
        const float4 v = *(const float4*)(src + (size_t)(m0 + row) * Dd + k0 + c4);
        const float va[4] = {v.x, v.y, v.z, v.w};
        half4v h, l;
#pragma unroll
        for (int q = 0; q < 4; ++q) {
            const _Float16 hi = (_Float16)va[q];
            h[q] = hi;
            l[q] = (_Float16)((va[q] - (float)hi) * 4096.0f);
        }
        *(half4v*)&lh[row * 72 + c4] = h;
        *(half4v*)&ll[row * 72 + c4] = l;
    }
    __syncthreads();
#pragma unroll
    for (int i = 0; i < 2; ++i) {
        const int lin = tid + i * 256;
        const int kc = lin >> 6;   // 0..7
        const int mm = lin & 63;
        const half8 h = *(const half8*)&lh[mm * 72 + kc * 8];
        const half8 l = *(const half8*)&ll[mm * 72 + kc * 8];
        const size_t g = (size_t)(k0 / 8 + kc) * nrows + m0 + mm;
        *(half8*)(dh + g * 8) = h;
        *(half8*)(dl + g * 8) = l;
    }
}

// ---------------------------------------------------------------------------
// Kernel 2: FUSED MFMA GEMM + ALIF scan, operand paths SWAPPED vs R9:
//  - A (xh/xl): wave-private rows -> DIRECT global->register, 1-ahead rotating
//    prefetch (zero redundancy, no LDS, no barriers for A).
//  - B (wh/wl): shared by all 4 waves -> global_load_lds into 32KB double-
//    buffered LDS, BK=64 super-stages (8 barriers total), conflict-free
//    16B-stride ds_read_b128 fragment reads.
// Per block-halfstage pipe traffic: L1 32->20KB, LDS 32->20KB vs R9.
// Tile M=256 (one batch b) x N=64, 4 waves. Epilogue = R9: dump C into two
// stride-32 LDS scan buffers (full 64KB reused), wave 0 scans 64 h, one
// atomicAdd into out[b]. XCD swizzle: 16 n-blocks of one batch on one XCD.
// ---------------------------------------------------------------------------
__global__ __launch_bounds__(256, 2) void gemm_fused(const _Float16* __restrict__ xh,
                                                     const _Float16* __restrict__ xl,
                                                     const _Float16* __restrict__ wh,
                                                     const _Float16* __restrict__ wl,
                                                     const float* __restrict__ bin,
                                                     const float* __restrict__ Wout,
                                                     float* __restrict__ out) {
    __shared__ float ldsS[16384];  // 64KB: K-loop uses first 32KB as B dbuf;
                                   // epilogue reuses all 64KB as scanbuf.
    _Float16* ldsB = (_Float16*)ldsS;  // [buf][arr][4096 halves] : ((buf*2+arr)*4096 + idx)

    const int tid = threadIdx.x;
    // XCD swizzle: j = id%8 = XCD slot; batch b ≡ j (mod 8); n-tile fast.
    const int id = blockIdx.x;          // 0..1023
    const int j  = id & 7;
    const int q  = id >> 3;             // 0..127
    const int nt = q & 15;              // n-tile 0..15 (64 cols each)
    const int b  = (q >> 4) * 8 + j;    // batch 0..63
    const int m0 = b * Tt;              // = b*256
    const int n0 = nt * 64;

    const int lane = tid & 63;
    const int wave = tid >> 6;          // 0..3, owns rows [64w, 64w+64)
    const int lr = lane & 31;
    const int lk = lane >> 5;

    floatx16 acc[2][2], accx[2][2];
#pragma unroll
    for (int mi = 0; mi < 2; ++mi)
#pragma unroll
        for (int ni = 0; ni < 2; ++ni)
#pragma unroll
            for (int r = 0; r < 16; ++r) { acc[mi][ni][r] = 0.0f; accx[mi][ni][r] = 0.0f; }

    // --- B staging: super-stage SS covers k-chunks [SS*8, SS*8+8) (64 k).
    // 512 chunks/array; thread handles 2 chunks/array (4 glds of 16B).
    // c_ in [0,512): kc = c_>>6, col = c_&63 -> per-wave 1KB contiguous src.
#define STAGE_B(buf, SS)                                                             \
    do {                                                                             \
        _Pragma("unroll")                                                            \
        for (int i_ = 0; i_ < 2; ++i_) {                                             \
            const int c_ = tid + i_ * 256;                                           \
            const int kc_ = c_ >> 6;                                                 \
            const int col_ = c_ & 63;                                                \
            const size_t g_ = ((size_t)((SS) * 8 + kc_) * Hh + n0 + col_) * 8;       \
            __builtin_amdgcn_global_load_lds(GPTR(wh + g_), LPTR(&ldsB[((buf) * 2 + 0) * 4096 + c_ * 8]), 16, 0, 0); \
            __builtin_amdgcn_global_load_lds(GPTR(wl + g_), LPTR(&ldsB[((buf) * 2 + 1) * 4096 + c_ * 8]), 16, 0, 0); \
        }                                                                            \
    } while (0)

    // --- A direct loads (wave-private rows): half-stage hs, kc = hs*2 + lk ---
    const size_t arow0 = (size_t)(m0 + wave * 64 + lr);  // +32 for mi=1
    half8 aset[2][4];  // [rot][ah0, ah1, al0, al1]
#define LOAD_A(rot, hs)                                                              \
    do {                                                                             \
        const size_t kA = (size_t)((hs) * 2 + lk) * Mm;                              \
        aset[rot][0] = *(const half8*)(xh + (kA + arow0) * 8);                       \
        aset[rot][1] = *(const half8*)(xh + (kA + arow0 + 32) * 8);                  \
        aset[rot][2] = *(const half8*)(xl + (kA + arow0) * 8);                       \
        aset[rot][3] = *(const half8*)(xl + (kA + arow0 + 32) * 8);                  \
    } while (0)

    STAGE_B(0, 0);
    LOAD_A(0, 0);

    for (int SS = 0; SS < 8; ++SS) {
        __syncthreads();  // B(SS) staged; other buf safe to overwrite
        if (SS < 7) STAGE_B((SS + 1) & 1, SS + 1);
        const int cur = SS & 1;
#pragma unroll
        for (int qq = 0; qq < 4; ++qq) {
            const int hs = SS * 4 + qq;
            const int rot = hs & 1;
            if (hs < 31) LOAD_A(rot ^ 1, hs + 1);

            // B fragments from LDS: kc_local = qq*2 + lk, col = ni*32 + lr
            half8 bh[2], bl[2];
#pragma unroll
            for (int ni = 0; ni < 2; ++ni) {
                const int ci = (qq * 2 + lk) * 64 + ni * 32 + lr;
                bh[ni] = *(const half8*)&ldsB[(cur * 2 + 0) * 4096 + ci * 8];
                bl[ni] = *(const half8*)&ldsB[(cur * 2 + 1) * 4096 + ci * 8];
            }
#pragma unroll
            for (int mi = 0; mi < 2; ++mi)
#pragma unroll
                for (int ni = 0; ni < 2; ++ni) {
                    acc[mi][ni]  = __builtin_amdgcn_mfma_f32_32x32x16_f16(aset[rot][mi],     bh[ni], acc[mi][ni], 0, 0, 0);
                    accx[mi][ni] = __builtin_amdgcn_mfma_f32_32x32x16_f16(aset[rot][mi],     bl[ni], accx[mi][ni], 0, 0, 0);
                    accx[mi][ni] = __builtin_amdgcn_mfma_f32_32x32x16_f16(aset[rot][2 + mi], bh[ni], accx[mi][ni], 0, 0, 0);
                }
        }
    }
#undef STAGE_B
#undef LOAD_A

    // ---------------- fused ALIF scan epilogue (R9-proven) ----------------
    __syncthreads();  // all K-loop LDS reads done; reuse ldsS as 2 scan buffers
    float* scanbuf = ldsS;  // buffer p at offset p*8192 floats (stride 32)

#pragma unroll
    for (int p = 0; p < 2; ++p) {
        const float bv = bin[n0 + p * 32 + lr];
        // C/D layout (32x32): col = lane&31, row = (r&3) + 8*(r>>2) + 4*lk
#pragma unroll
        for (int mi = 0; mi < 2; ++mi)
#pragma unroll
            for (int r = 0; r < 16; ++r) {
                const int row = (r & 3) + 8 * (r >> 2) + 4 * lk;
                const int t = wave * 64 + mi * 32 + row;   // m_local == timestep
                scanbuf[p * 8192 + t * 32 + lr] =
                    acc[mi][p][r] + accx[mi][p][r] * (1.0f / 4096.0f) + bv;
            }
    }
    __syncthreads();

    // Wave 0 scans all 64 h (lane = h - n0); waves 1-3 exit immediately.
    if (wave == 0) {
        const float* sb = scanbuf + (lane >> 5) * 8192 + (lane & 31);
        float mem = 0.0f, adapt = 0.0f, cnt = 0.0f;
#pragma unroll 8
        for (int t = 0; t < Tt; ++t) {
            const float v = sb[t * 32];
            mem = 0.9f * mem + v - adapt;
            const float spk = (mem > 0.0f) ? 1.0f : 0.0f;
            adapt += 0.1f * spk;
            mem -= spk;
            cnt += spk;
        }
        float val = cnt * Wout[n0 + lane] * (1.0f / (float)Tt);
#pragma unroll
        for (int off = 32; off > 0; off >>= 1) val += __shfl_down(val, off, 64);
        if (lane == 0) atomicAdd(&out[b], val);
    }
}

// ---------------------------------------------------------------------------
// Fallback fp32 SIMT GEMM + scan (proven) in case ws is too small.
// ---------------------------------------------------------------------------
#define BK 16
#define BMP 132
__global__ __launch_bounds__(256) void gemm_pre(const float* __restrict__ x,
                                                const float* __restrict__ Win,
                                                const float* __restrict__ bin,
                                                float* __restrict__ pre) {
    __shared__ float As[BK][BMP];
    __shared__ float Bs[BK][BMP];
    const int tid = threadIdx.x;
    const int m0 = blockIdx.y * 128;
    const int n0 = blockIdx.x * 128;
    const int tx = tid & 15;
    const int ty = tid >> 4;
    float acc[8][8];
#pragma unroll
    for (int i = 0; i < 8; ++i)
#pragma unroll
        for (int jj = 0; jj < 8; ++jj) acc[i][jj] = 0.0f;
    const float* Aptr = x + (size_t)m0 * Dd;
    const float* Bptr = Win + (size_t)n0 * Dd;
    for (int k0 = 0; k0 < Dd; k0 += BK) {
#pragma unroll
        for (int i = 0; i < 2; ++i) {
            const int lin = tid + i * 256;
            const int row = lin >> 2;
            const int kq = (lin & 3) << 2;
            const float4 av = *(const float4*)(Aptr + (size_t)row * Dd + k0 + kq);
            const float4 bv = *(const float4*)(Bptr + (size_t)row * Dd + k0 + kq);
            As[kq + 0][row] = av.x; As[kq + 1][row] = av.y;
            As[kq + 2][row] = av.z; As[kq + 3][row] = av.w;
            Bs[kq + 0][row] = bv.x; Bs[kq + 1][row] = bv.y;
            Bs[kq + 2][row] = bv.z; Bs[kq + 3][row] = bv.w;
        }
        __syncthreads();
#pragma unroll
        for (int kk = 0; kk < BK; ++kk) {
            const float4 a0 = *(const float4*)&As[kk][ty * 4];
            const float4 a1 = *(const float4*)&As[kk][ty * 4 + 64];
            const float4 b0 = *(const float4*)&Bs[kk][tx * 4];
            const float4 b1 = *(const float4*)&Bs[kk][tx * 4 + 64];
            const float a[8] = {a0.x, a0.y, a0.z, a0.w, a1.x, a1.y, a1.z, a1.w};
            const float b[8] = {b0.x, b0.y, b0.z, b0.w, b1.x, b1.y, b1.z, b1.w};
#pragma unroll
            for (int i = 0; i < 8; ++i)
#pragma unroll
                for (int jj = 0; jj < 8; ++jj) acc[i][jj] += a[i] * b[jj];
        }
        __syncthreads();
    }
#pragma unroll
    for (int i = 0; i < 8; ++i) {
        const int m = m0 + ((i < 4) ? (ty * 4 + i) : (64 + ty * 4 + i - 4));
#pragma unroll
        for (int half = 0; half < 2; ++half) {
            const int n = n0 + tx * 4 + half * 64;
            float4 v;
            v.x = acc[i][half * 4 + 0] + bin[n + 0];
            v.y = acc[i][half * 4 + 1] + bin[n + 1];
            v.z = acc[i][half * 4 + 2] + bin[n + 2];
            v.w = acc[i][half * 4 + 3] + bin[n + 3];
            *(float4*)(pre + (size_t)m * Hh + n) = v;
        }
    }
}

__global__ __launch_bounds__(64) void init_out(const float* __restrict__ bout,
                                               float* __restrict__ out) {
    out[threadIdx.x] = bout[0];
}

__global__ __launch_bounds__(64) void alif_scan(const float* __restrict__ pre,
                                                const float* __restrict__ Wout,
                                                float* __restrict__ out) {
    const int h = blockIdx.x * 64 + threadIdx.x;
    const int b = blockIdx.y;
    const float* p = pre + (size_t)b * Tt * Hh + h;

    float buf[32];
#pragma unroll
    for (int jj = 0; jj < 32; ++jj) buf[jj] = p[(size_t)jj * Hh];

    float mem = 0.0f, adapt = 0.0f, cnt = 0.0f;
    for (int t0 = 0; t0 < Tt; t0 += 32) {
        float cur[32];
#pragma unroll
        for (int jj = 0; jj < 32; ++jj) cur[jj] = buf[jj];
        if (t0 + 32 < Tt) {
#pragma unroll
            for (int jj = 0; jj < 32; ++jj) buf[jj] = p[(size_t)(t0 + 32 + jj) * Hh];
        }
#pragma unroll
        for (int jj = 0; jj < 32; ++jj) {
            mem = 0.9f * mem + cur[jj] - adapt;
            const float spk = (mem > 0.0f) ? 1.0f : 0.0f;
            adapt += 0.1f * spk;
            mem -= spk;
            cnt += spk;
        }
    }

    float val = cnt * Wout[h] * (1.0f / (float)Tt);
#pragma unroll
    for (int off = 32; off > 0; off >>= 1) val += __shfl_down(val, off, 64);
    if (threadIdx.x == 0) atomicAdd(&out[b], val);
}

extern "C" void kernel_launch(void* const* d_in, const int* in_sizes, int n_in,
                              void* d_out, int out_size, void* d_ws, size_t ws_size,
                              hipStream_t stream) {
    const float* x    = (const float*)d_in[0];
    const float* Win  = (const float*)d_in[1];
    const float* bin  = (const float*)d_in[2];
    const float* Wout = (const float*)d_in[3];
    const float* bout = (const float*)d_in[4];
    float* out = (float*)d_out;

    const size_t xh_bytes = (size_t)Mm * Dd * 2;   // 16 MiB
    const size_t wh_bytes = (size_t)Hh * Dd * 2;   // 1 MiB
    const size_t need = 2 * xh_bytes + 2 * wh_bytes + 4096;

    if (ws_size >= need) {
        char* base = (char*)d_ws;
        _Float16* xh = (_Float16*)base;
        _Float16* xl = (_Float16*)(base + xh_bytes);
        _Float16* wh = (_Float16*)(base + 2 * xh_bytes);
        _Float16* wl = (_Float16*)(base + 2 * xh_bytes + wh_bytes);

        // x: 256 row-tiles of 64; W: 16 row-tiles of 64. 8 k-tiles of 64.
        convert_t<<<dim3(8, 272), 256, 0, stream>>>(x, Win, xh, xl, wh, wl, bout, out);

        gemm_fused<<<1024, 256, 0, stream>>>(xh, xl, wh, wl, bin, Wout, out);
    } else {
        float* pre = (float*)d_ws;  // needs 64 MiB
        init_out<<<1, 64, 0, stream>>>(bout, out);
        dim3 g1(Hh / 128, Mm / 128);
        gemm_pre<<<g1, 256, 0, stream>>>(x, Win, bin, pre);
        alif_scan<<<dim3(Hh / 64, Bb), 64, 0, stream>>>(pre, Wout, out);
    }
}